// Round 1
// baseline (1099.176 us; speedup 1.0000x reference)
//
#include <hip/hip_runtime.h>
#include <stdint.h>

typedef int   v4i __attribute__((ext_vector_type(4)));
typedef float v4f __attribute__((ext_vector_type(4)));

// LDS map (bank-conflict-free act layout):
//   two act slots of 12288 B each, slot s base = s*SLOT_SZ
//   hi act byte (l, k, b): s*SLOT_SZ + l*2048 + (k>>4)*256 + b*16 + (k&15)
//   lo act byte: +LO_OFF
//   B-frag read for (l, kh): base + l*2048 + kh*1024 + lane*16  -> linear in lane
#define SLOT_SZ  12288
#define LO_OFF   6144
#define SMEM_SZ  (2*SLOT_SZ)   // 24576

#define QW   1436.84056f      // 127/s, s = 1/sqrt(128)
#define C1f  4.38394754e-5f   // s*8/127^2  (hi-accum scale)
#define C2f  3.45193507e-7f   // C1/127     (lo-accum scale)
#define L2E  1.44269504f
// folded gate-combine constants: sigmoid gates carry -log2e, tanh gates 2*log2e
#define CR1  (-(L2E)*C1f)
#define CR2  (-(L2E)*C2f)
#define CX1  (2.0f*L2E*C1f)
#define CX2  (2.0f*L2E*C2f)

#define MFMA(A,B,C) __builtin_amdgcn_mfma_i32_16x16x64_i8(A, B, C, 0, 0, 0)

// i8 weight image (unchanged): blk = l*12 + o*2 + kh; o: 0 Rx,1 Rh,2 Zx,3 Zh,4 Nx,5 Nh.
// lane(g=lane&15, q=lane>>4) holds W[row g][k = kh*64 + q*16 + j], j=0..15.
__global__ void prep_weights(const float* __restrict__ Wih,
                             const float* __restrict__ Whh,
                             int8_t* __restrict__ img) {
  int bid = blockIdx.x, lane = threadIdx.x;          // 288 blocks x 64
  int w = bid / 36, blk = bid % 36;
  int l = blk / 12, rem = blk % 12, o = rem >> 1, kh = rem & 1;
  const float* M = (o & 1) ? Whh : Wih;
  int row = (o >> 1) * 128 + w * 16 + (lane & 15);
  int k0 = kh * 64 + (lane >> 4) * 16;
  const float* src = M + l * 49152 + row * 128 + k0;
  int words[4];
  #pragma unroll
  for (int j4 = 0; j4 < 4; ++j4) {
    unsigned wd = 0;
    #pragma unroll
    for (int j = 0; j < 4; ++j) {
      int q = (int)rintf(src[j4 * 4 + j] * QW);
      wd |= ((unsigned)(q & 255)) << (8 * j);
    }
    words[j4] = (int)wd;
  }
  *(v4i*)(img + (((long)bid) * 64 + lane) * 16) = *(const v4i*)words;
}

#define DECL_ACC v4i aRh={0,0,0,0},aRl={0,0,0,0},aZh={0,0,0,0},aZl={0,0,0,0}, \
                     aXh={0,0,0,0},aXl={0,0,0,0},aHh={0,0,0,0},aHl={0,0,0,0}

#define HMFMA(L,H0,LL0,H1,LL1) do { \
  aRh = MFMA(wr[(L)*12+2],  H0,  aRh);  aRl = MFMA(wr[(L)*12+2],  LL0, aRl); \
  aZh = MFMA(wr[(L)*12+6],  H0,  aZh);  aZl = MFMA(wr[(L)*12+6],  LL0, aZl); \
  aHh = MFMA(wr[(L)*12+10], H0,  aHh);  aHl = MFMA(wr[(L)*12+10], LL0, aHl); \
  aRh = MFMA(wr[(L)*12+3],  H1,  aRh);  aRl = MFMA(wr[(L)*12+3],  LL1, aRl); \
  aZh = MFMA(wr[(L)*12+7],  H1,  aZh);  aZl = MFMA(wr[(L)*12+7],  LL1, aZl); \
  aHh = MFMA(wr[(L)*12+11], H1,  aHh);  aHl = MFMA(wr[(L)*12+11], LL1, aHl); \
} while(0)

#define XMFMA(L,H0,LL0,H1,LL1) do { \
  aRh = MFMA(wr[(L)*12+0],  H0,  aRh);  aRl = MFMA(wr[(L)*12+0],  LL0, aRl); \
  aZh = MFMA(wr[(L)*12+4],  H0,  aZh);  aZl = MFMA(wr[(L)*12+4],  LL0, aZl); \
  aXh = MFMA(wr[(L)*12+8],  H0,  aXh);  aXl = MFMA(wr[(L)*12+8],  LL0, aXl); \
  aRh = MFMA(wr[(L)*12+1],  H1,  aRh);  aRl = MFMA(wr[(L)*12+1],  LL1, aRl); \
  aZh = MFMA(wr[(L)*12+5],  H1,  aZh);  aZl = MFMA(wr[(L)*12+5],  LL1, aZl); \
  aXh = MFMA(wr[(L)*12+9],  H1,  aXh);  aXl = MFMA(wr[(L)*12+9],  LL1, aXl); \
} while(0)

#define EW_WRITE(L, SN) do { \
  unsigned hiw = 0, low = 0; \
  _Pragma("unroll") \
  for (int r = 0; r < 4; ++r) { \
    float gR = fmaf(CR1, (float)aRh[r], fmaf(CR2, (float)aRl[r], bR[L][r])); \
    float gZ = fmaf(CR1, (float)aZh[r], fmaf(CR2, (float)aZl[r], bZ[L][r])); \
    float gX = fmaf(CX1, (float)aXh[r], fmaf(CX2, (float)aXl[r], bX[L][r])); \
    float gH = fmaf(CX1, (float)aHh[r], fmaf(CX2, (float)aHl[r], bH[L][r])); \
    float rg = __builtin_amdgcn_rcpf(1.f + __builtin_amdgcn_exp2f(gR)); \
    float zg = __builtin_amdgcn_rcpf(1.f + __builtin_amdgcn_exp2f(gZ)); \
    float u  = __builtin_amdgcn_rcpf(1.f + __builtin_amdgcn_exp2f(fmaf(rg, gH, gX))); \
    float ng = fmaf(-2.f, u, 1.f); \
    float hn = fmaf(zg, hst[L][r] - ng, ng); \
    hst[L][r] = hn; \
    float f = hn * 15.875f, fhi = rintf(f); \
    hiw |= ((unsigned)(((int)fhi) & 255)) << (8 * r); \
    low |= ((unsigned)(((int)rintf((f - fhi) * 127.f)) & 255)) << (8 * r); \
  } \
  *(unsigned*)(ewb + (SN) + (L)*2048)          = hiw; \
  *(unsigned*)(ewb + (SN) + (L)*2048 + LO_OFF) = low; \
} while(0)

__global__ __launch_bounds__(512, 2)
void gru_main(const float* __restrict__ hiddens, const float* __restrict__ bih,
              const float* __restrict__ bhh, const float* __restrict__ fcw,
              const float* __restrict__ fcb, const int8_t* __restrict__ img,
              float* __restrict__ out) {
  extern __shared__ char smem[];
  const int tid = threadIdx.x, wg = blockIdx.x;
  const int lane = tid & 63, w = tid >> 6, col = lane & 15, q = lane >> 4;

  // ---- ALL 36 weight frags in registers ----
  v4i wr[36];
  #pragma unroll
  for (int i = 0; i < 36; ++i)
    wr[i] = *(const v4i*)(img + (((long)(w * 36 + i)) * 64 + lane) * 16);

  // ---- fc i8 A-frags in wave-0 registers (was LDS) ----
  v4i fw0 = {0, 0, 0, 0}, fw1 = {0, 0, 0, 0};
  if (w == 0 && col < 2) {
    #pragma unroll
    for (int kh = 0; kh < 2; ++kh) {
      const float* src = fcw + col * 128 + kh * 64 + q * 16;
      int words[4];
      #pragma unroll
      for (int j4 = 0; j4 < 4; ++j4) {
        unsigned wd = 0;
        #pragma unroll
        for (int j = 0; j < 4; ++j) {
          int qv = (int)rintf(src[j4 * 4 + j] * QW);
          wd |= ((unsigned)(qv & 255)) << (8 * j);
        }
        words[j4] = (int)wd;
      }
      v4i tv = {words[0], words[1], words[2], words[3]};
      if (kh == 0) fw0 = tv; else fw1 = tv;
    }
  }

  // ---- pre-scaled biases in registers (was LDS, re-read every phase) ----
  v4f bR[3], bZ[3], bX[3], bH[3];
  {
    const int rowb = w * 16 + q * 4;
    #pragma unroll
    for (int l = 0; l < 3; ++l) {
      #pragma unroll
      for (int r = 0; r < 4; ++r) {
        int idx = rowb + r;
        bR[l][r] = -L2E * (bih[l * 384 + idx]       + bhh[l * 384 + idx]);
        bZ[l][r] = -L2E * (bih[l * 384 + 128 + idx] + bhh[l * 384 + 128 + idx]);
        bX[l][r] = 2.0f * L2E * bih[l * 384 + 256 + idx];
        bH[l][r] = 2.0f * L2E * bhh[l * 384 + 256 + idx];
      }
    }
  }

  // ---- act slot0 init (hi/lo), new chunked layout ----
  for (int i = tid; i < 6144; i += 512) {
    int l = i >> 11, b = (i >> 7) & 15, h = i & 127;
    float v = hiddens[((long)(wg * 16 + b)) * 384 + l * 128 + h];
    float f = v * 15.875f, fhi = rintf(f);
    int addr = l * 2048 + (h >> 4) * 256 + b * 16 + (h & 15);
    *(int8_t*)(smem + addr)          = (int8_t)(int)fhi;
    *(int8_t*)(smem + addr + LO_OFF) = (int8_t)(int)rintf((f - fhi) * 127.f);
  }

  // ---- h-state in regs: hst[l][r] = h[l][w*16+q*4+r][batch=col] ----
  v4f hst[3];
  #pragma unroll
  for (int l = 0; l < 3; ++l)
    #pragma unroll
    for (int r = 0; r < 4; ++r)
      hst[l][r] = hiddens[((long)(wg * 16 + col)) * 384 + l * 128 + w * 16 + q * 4 + r];

  const float fcb0 = fcb[0], fcb1 = fcb[1];
  __syncthreads();

  const char* fragb = smem + lane * 16;                 // linear frag base
  char* ewb = smem + w * 256 + col * 16 + q * 4;        // EW b32 write base

  // prefetched h-frags for the upcoming l=0 phase (t=0: slot 0, layer 0)
  v4i p0h = *(const v4i*)(fragb + 0);
  v4i p0l = *(const v4i*)(fragb + 0 + LO_OFF);
  v4i p1h = *(const v4i*)(fragb + 1024);
  v4i p1l = *(const v4i*)(fragb + 1024 + LO_OFF);
  v4i c2h0, c2l0, c2h1, c2l1;                           // layer-2 read-slot cache
  v4i n0h, n0l, n1h, n1l, x0h, x0l, x1h, x1l;

  #pragma unroll 1
  for (int t = 0; t < 256; ++t) {
    const int so = (t & 1) * SLOT_SZ;
    const int sn = SLOT_SZ - so;

    // ================= layer 0 =================
    {
      DECL_ACC;
      // x-frags = prev-step layer-2 acts (read slot); double as l=2 h cache
      c2h0 = *(const v4i*)(fragb + so + 2 * 2048);
      c2l0 = *(const v4i*)(fragb + so + 2 * 2048 + LO_OFF);
      c2h1 = *(const v4i*)(fragb + so + 2 * 2048 + 1024);
      c2l1 = *(const v4i*)(fragb + so + 2 * 2048 + 1024 + LO_OFF);
      HMFMA(0, p0h, p0l, p1h, p1l);          // h operands already in regs
      if (t > 0) XMFMA(0, c2h0, c2l0, c2h1, c2l1);
      // prefetch l=1 h-frags (stable since last step) under EW latency
      n0h = *(const v4i*)(fragb + so + 2048);
      n0l = *(const v4i*)(fragb + so + 2048 + LO_OFF);
      n1h = *(const v4i*)(fragb + so + 2048 + 1024);
      n1l = *(const v4i*)(fragb + so + 2048 + 1024 + LO_OFF);
      EW_WRITE(0, sn);
      __syncthreads();
    }
    // ================= layer 1 =================
    {
      DECL_ACC;
      x0h = *(const v4i*)(fragb + sn + 0);               // fresh layer-0 acts
      x0l = *(const v4i*)(fragb + sn + 0 + LO_OFF);
      x1h = *(const v4i*)(fragb + sn + 1024);
      x1l = *(const v4i*)(fragb + sn + 1024 + LO_OFF);
      HMFMA(1, n0h, n0l, n1h, n1l);
      XMFMA(1, x0h, x0l, x1h, x1l);
      EW_WRITE(1, sn);
      __syncthreads();
    }
    // ================= layer 2 =================
    {
      DECL_ACC;
      x0h = *(const v4i*)(fragb + sn + 2048);            // fresh layer-1 acts
      x0l = *(const v4i*)(fragb + sn + 2048 + LO_OFF);
      x1h = *(const v4i*)(fragb + sn + 2048 + 1024);
      x1l = *(const v4i*)(fragb + sn + 2048 + 1024 + LO_OFF);
      HMFMA(2, c2h0, c2l0, c2h1, c2l1);                  // cached, no LDS read
      XMFMA(2, x0h, x0l, x1h, x1l);
      // prefetch next-step l=0 h-frags (layer-0 acts written this step, synced)
      p0h = *(const v4i*)(fragb + sn + 0);
      p0l = *(const v4i*)(fragb + sn + 0 + LO_OFF);
      p1h = *(const v4i*)(fragb + sn + 1024);
      p1l = *(const v4i*)(fragb + sn + 1024 + LO_OFF);
      EW_WRITE(2, sn);
      __syncthreads();
    }
    // ---- FC epilogue (wave 0): layer-2 acts just written (write slot) ----
    if (w == 0) {
      v4i dh = {0, 0, 0, 0}, dl = {0, 0, 0, 0};
      v4i fh0 = *(const v4i*)(fragb + sn + 2 * 2048);
      v4i fl0 = *(const v4i*)(fragb + sn + 2 * 2048 + LO_OFF);
      v4i fh1 = *(const v4i*)(fragb + sn + 2 * 2048 + 1024);
      v4i fl1 = *(const v4i*)(fragb + sn + 2 * 2048 + 1024 + LO_OFF);
      dh = MFMA(fw0, fh0, dh);  dl = MFMA(fw0, fl0, dl);
      dh = MFMA(fw1, fh1, dh);  dl = MFMA(fw1, fl1, dl);
      if (q == 0) {
        float2 o2;
        o2.x = fcb0 + C1f * (float)dh[0] + C2f * (float)dl[0];
        o2.y = fcb1 + C1f * (float)dh[1] + C2f * (float)dl[1];
        *(float2*)(out + (((long)(wg * 16 + col)) * 256 + t) * 2) = o2;
      }
    }
  }
}

extern "C" void kernel_launch(void* const* d_in, const int* in_sizes, int n_in,
                              void* d_out, int out_size, void* d_ws, size_t ws_size,
                              hipStream_t stream) {
  (void)in_sizes; (void)n_in; (void)out_size; (void)ws_size;
  const float* hiddens = (const float*)d_in[0];
  const float* Wih     = (const float*)d_in[1];
  const float* Whh     = (const float*)d_in[2];
  const float* bih     = (const float*)d_in[3];
  const float* bhh     = (const float*)d_in[4];
  const float* fcw     = (const float*)d_in[5];
  const float* fcb     = (const float*)d_in[6];
  int8_t* img = (int8_t*)d_ws;   // 288 KB weight image
  float* out = (float*)d_out;

  prep_weights<<<288, 64, 0, stream>>>(Wih, Whh, img);
  gru_main<<<64, 512, SMEM_SZ, stream>>>(hiddens, bih, bhh, fcw, fcb, img, out);
}

// Round 2
// 836.043 us; speedup vs baseline: 1.3147x; 1.3147x over previous
//
#include <hip/hip_runtime.h>
#include <stdint.h>

typedef int   v4i __attribute__((ext_vector_type(4)));
typedef float v4f __attribute__((ext_vector_type(4)));

// LDS map (bank-conflict-free act layout, r0 register structure):
//   two act slots of 12288 B each, slot s base = s*SLOT_SZ
//   hi act byte (l, k, b): s*SLOT_SZ + l*2048 + (k>>4)*256 + b*16 + (k&15)
//   lo act byte: +LO_OFF
//   B-frag read for (l, kh): base + l*2048 + kh*1024 + lane*16  -> linear in lane
//   BIAS_OFF: fp32 PRE-SCALED bias [l][type R,Z,NX,NH][h]  (6144 B)
//   FC_OFF:   fc i8 A-frags, 2 blocks of 1KB
#define SLOT_SZ  12288
#define LO_OFF   6144
#define BIAS_OFF (2*SLOT_SZ)            // 24576
#define FC_OFF   (BIAS_OFF + 6144)      // 30720
#define SMEM_SZ  (FC_OFF + 2048)        // 32768

#define QW   1436.84056f      // 127/s, s = 1/sqrt(128)
#define C1f  4.38394754e-5f   // s*8/127^2  (hi-accum scale)
#define C2f  3.45193507e-7f   // C1/127     (lo-accum scale)
#define L2E  1.44269504f
// folded gate-combine constants: sigmoid gates carry -log2e, tanh gates 2*log2e
#define CR1  (-(L2E)*C1f)
#define CR2  (-(L2E)*C2f)
#define CX1  (2.0f*L2E*C1f)
#define CX2  (2.0f*L2E*C2f)

#define MFMA(A,B,C) __builtin_amdgcn_mfma_i32_16x16x64_i8(A, B, C, 0, 0, 0)

// i8 weight image (unchanged): blk = l*12 + o*2 + kh; o: 0 Rx,1 Rh,2 Zx,3 Zh,4 Nx,5 Nh.
// lane(g=lane&15, q=lane>>4) holds W[row g][k = kh*64 + q*16 + j], j=0..15.
__global__ void prep_weights(const float* __restrict__ Wih,
                             const float* __restrict__ Whh,
                             int8_t* __restrict__ img) {
  int bid = blockIdx.x, lane = threadIdx.x;          // 288 blocks x 64
  int w = bid / 36, blk = bid % 36;
  int l = blk / 12, rem = blk % 12, o = rem >> 1, kh = rem & 1;
  const float* M = (o & 1) ? Whh : Wih;
  int row = (o >> 1) * 128 + w * 16 + (lane & 15);
  int k0 = kh * 64 + (lane >> 4) * 16;
  const float* src = M + l * 49152 + row * 128 + k0;
  int words[4];
  #pragma unroll
  for (int j4 = 0; j4 < 4; ++j4) {
    unsigned wd = 0;
    #pragma unroll
    for (int j = 0; j < 4; ++j) {
      int q = (int)rintf(src[j4 * 4 + j] * QW);
      wd |= ((unsigned)(q & 255)) << (8 * j);
    }
    words[j4] = (int)wd;
  }
  *(v4i*)(img + (((long)bid) * 64 + lane) * 16) = *(const v4i*)words;
}

__global__ __launch_bounds__(512, 2)
void gru_main(const float* __restrict__ hiddens, const float* __restrict__ bih,
              const float* __restrict__ bhh, const float* __restrict__ fcw,
              const float* __restrict__ fcb, const int8_t* __restrict__ img,
              float* __restrict__ out) {
  extern __shared__ char smem[];
  const int tid = threadIdx.x, wg = blockIdx.x;
  const int lane = tid & 63, w = tid >> 6, col = lane & 15, q = lane >> 4;

  // ---- ALL 36 weight frags in registers ----
  v4i wr[36];
  #pragma unroll
  for (int i = 0; i < 36; ++i)
    wr[i] = *(const v4i*)(img + (((long)(w * 36 + i)) * 64 + lane) * 16);

  // ---- fc i8 A-frags in LDS ----
  if (tid < 128) {
    int kh = tid >> 6, ln = tid & 63, c2 = ln & 15, q2 = ln >> 4;
    int words[4] = {0, 0, 0, 0};
    if (c2 < 2) {
      const float* src = fcw + c2 * 128 + kh * 64 + q2 * 16;
      #pragma unroll
      for (int j4 = 0; j4 < 4; ++j4) {
        unsigned wd = 0;
        #pragma unroll
        for (int j = 0; j < 4; ++j) {
          int qv = (int)rintf(src[j4 * 4 + j] * QW);
          wd |= ((unsigned)(qv & 255)) << (8 * j);
        }
        words[j4] = (int)wd;
      }
    }
    *(v4i*)(smem + FC_OFF + kh * 1024 + ln * 16) = *(const v4i*)words;
  }
  // ---- bias table in LDS, PRE-SCALED for exp2-form gates ----
  for (int i = tid; i < 1536; i += 512) {
    int l = i >> 9, type = (i >> 7) & 3, h = i & 127;
    float bv;
    if      (type == 0) bv = -L2E * (bih[l * 384 + h]       + bhh[l * 384 + h]);
    else if (type == 1) bv = -L2E * (bih[l * 384 + 128 + h] + bhh[l * 384 + 128 + h]);
    else if (type == 2) bv = 2.0f * L2E * bih[l * 384 + 256 + h];
    else                bv = 2.0f * L2E * bhh[l * 384 + 256 + h];
    *(float*)(smem + BIAS_OFF + i * 4) = bv;
  }
  // ---- act slot0 init (hi/lo), chunked layout ----
  for (int i = tid; i < 6144; i += 512) {
    int l = i >> 11, b = (i >> 7) & 15, h = i & 127;
    float v = hiddens[((long)(wg * 16 + b)) * 384 + l * 128 + h];
    float f = v * 15.875f, fhi = rintf(f);
    int addr = l * 2048 + (h >> 4) * 256 + b * 16 + (h & 15);
    *(int8_t*)(smem + addr)          = (int8_t)(int)fhi;
    *(int8_t*)(smem + addr + LO_OFF) = (int8_t)(int)rintf((f - fhi) * 127.f);
  }
  // ---- h-state in regs: hst[l][r] = h[l][w*16+q*4+r][batch=col] ----
  v4f hst[3];
  #pragma unroll
  for (int l = 0; l < 3; ++l)
    #pragma unroll
    for (int r = 0; r < 4; ++r)
      hst[l][r] = hiddens[((long)(wg * 16 + col)) * 384 + l * 128 + w * 16 + q * 4 + r];

  const float fcb0 = fcb[0], fcb1 = fcb[1];
  __syncthreads();

  const char* fragb = smem + lane * 16;                 // linear frag base
  char* ewb = smem + w * 256 + col * 16 + q * 4;        // EW b32 write base (2-way, free)
  const char* biasb = smem + BIAS_OFF + (w * 16 + q * 4) * 4;

  v4i c2h[2], c2l[2];   // cached layer-2 read-slot frags (l0-x == l2-h data)

  #pragma unroll 1
  for (int t = 0; t < 256; ++t) {
    const int so = (t & 1) * SLOT_SZ;
    const int sn = SLOT_SZ - so;
    #pragma unroll
    for (int l = 0; l < 3; ++l) {
      // bias prefetch (independent of everything in this phase)
      v4f bRv = *(const v4f*)(biasb + (l * 4 + 0) * 512);
      v4f bZv = *(const v4f*)(biasb + (l * 4 + 1) * 512);
      v4f bXv = *(const v4f*)(biasb + (l * 4 + 2) * 512);
      v4f bHv = *(const v4f*)(biasb + (l * 4 + 3) * 512);
      v4i aRh = {0,0,0,0}, aRl = {0,0,0,0}, aZh = {0,0,0,0}, aZl = {0,0,0,0};
      v4i aXh = {0,0,0,0}, aXl = {0,0,0,0}, aHh = {0,0,0,0}, aHl = {0,0,0,0};
      // ---- x side (on the serial chain: issue first) ----
      if (l > 0 || t > 0) {
        #pragma unroll
        for (int kh = 0; kh < 2; ++kh) {
          v4i xh, xl;
          if (l == 0) {           // x = prev-step layer2 acts (read slot); cache
            xh = *(const v4i*)(fragb + so + 2 * 2048 + kh * 1024);
            xl = *(const v4i*)(fragb + so + 2 * 2048 + kh * 1024 + LO_OFF);
            c2h[kh] = xh; c2l[kh] = xl;
          } else {                // x = fresh layer l-1 acts (write slot)
            xh = *(const v4i*)(fragb + sn + (l - 1) * 2048 + kh * 1024);
            xl = *(const v4i*)(fragb + sn + (l - 1) * 2048 + kh * 1024 + LO_OFF);
          }
          aRh = MFMA(wr[l*12 + 0 + kh], xh, aRh);
          aRl = MFMA(wr[l*12 + 0 + kh], xl, aRl);
          aZh = MFMA(wr[l*12 + 4 + kh], xh, aZh);
          aZl = MFMA(wr[l*12 + 4 + kh], xl, aZl);
          aXh = MFMA(wr[l*12 + 8 + kh], xh, aXh);
          aXl = MFMA(wr[l*12 + 8 + kh], xl, aXl);
        }
      }
      // ---- h side ----
      #pragma unroll
      for (int kh = 0; kh < 2; ++kh) {
        v4i hh, hl;
        if (l == 2) {             // same bytes l0-x read this step
          if (t == 0) { c2h[kh] = *(const v4i*)(fragb + so + 2 * 2048 + kh * 1024);
                        c2l[kh] = *(const v4i*)(fragb + so + 2 * 2048 + kh * 1024 + LO_OFF); }
          hh = c2h[kh]; hl = c2l[kh];
        } else {
          hh = *(const v4i*)(fragb + so + l * 2048 + kh * 1024);
          hl = *(const v4i*)(fragb + so + l * 2048 + kh * 1024 + LO_OFF);
        }
        aRh = MFMA(wr[l*12 + 2 + kh], hh, aRh);
        aRl = MFMA(wr[l*12 + 2 + kh], hl, aRl);
        aZh = MFMA(wr[l*12 + 6 + kh], hh, aZh);
        aZl = MFMA(wr[l*12 + 6 + kh], hl, aZl);
        aHh = MFMA(wr[l*12 + 10 + kh], hh, aHh);
        aHl = MFMA(wr[l*12 + 10 + kh], hl, aHl);
      }
      // ---- lean EW: exp2-form gates, folded constants, fp32 state ----
      unsigned hiw = 0, low = 0;
      #pragma unroll
      for (int r = 0; r < 4; ++r) {
        float gR = fmaf(CR1, (float)aRh[r], fmaf(CR2, (float)aRl[r], bRv[r]));
        float gZ = fmaf(CR1, (float)aZh[r], fmaf(CR2, (float)aZl[r], bZv[r]));
        float gX = fmaf(CX1, (float)aXh[r], fmaf(CX2, (float)aXl[r], bXv[r]));
        float gH = fmaf(CX1, (float)aHh[r], fmaf(CX2, (float)aHl[r], bHv[r]));
        float rg = __builtin_amdgcn_rcpf(1.f + __builtin_amdgcn_exp2f(gR));
        float zg = __builtin_amdgcn_rcpf(1.f + __builtin_amdgcn_exp2f(gZ));
        float u  = __builtin_amdgcn_rcpf(1.f + __builtin_amdgcn_exp2f(fmaf(rg, gH, gX)));
        float ng = fmaf(-2.f, u, 1.f);
        float hn = fmaf(zg, hst[l][r] - ng, ng);
        hst[l][r] = hn;
        float f = hn * 15.875f, fhi = rintf(f);
        hiw |= ((unsigned)(((int)fhi) & 255)) << (8 * r);
        low |= ((unsigned)(((int)rintf((f - fhi) * 127.f)) & 255)) << (8 * r);
      }
      *(unsigned*)(ewb + sn + l * 2048)          = hiw;
      *(unsigned*)(ewb + sn + l * 2048 + LO_OFF) = low;
      __syncthreads();
    }
    // ---- FC epilogue (wave 0): reads layer-2 acts just written (write slot) ----
    if (w == 0) {
      v4i dh = {0,0,0,0}, dl = {0,0,0,0};
      #pragma unroll
      for (int kh = 0; kh < 2; ++kh) {
        v4i xh = *(const v4i*)(fragb + sn + 2 * 2048 + kh * 1024);
        v4i xl = *(const v4i*)(fragb + sn + 2 * 2048 + kh * 1024 + LO_OFF);
        v4i fw = *(const v4i*)(smem + FC_OFF + kh * 1024 + lane * 16);
        dh = MFMA(fw, xh, dh);
        dl = MFMA(fw, xl, dl);
      }
      if (q == 0) {
        float2 o2;
        o2.x = fcb0 + C1f * (float)dh[0] + C2f * (float)dl[0];
        o2.y = fcb1 + C1f * (float)dh[1] + C2f * (float)dl[1];
        *(float2*)(out + (((long)(wg * 16 + col)) * 256 + t) * 2) = o2;
      }
    }
  }
}

extern "C" void kernel_launch(void* const* d_in, const int* in_sizes, int n_in,
                              void* d_out, int out_size, void* d_ws, size_t ws_size,
                              hipStream_t stream) {
  (void)in_sizes; (void)n_in; (void)out_size; (void)ws_size;
  const float* hiddens = (const float*)d_in[0];
  const float* Wih     = (const float*)d_in[1];
  const float* Whh     = (const float*)d_in[2];
  const float* bih     = (const float*)d_in[3];
  const float* bhh     = (const float*)d_in[4];
  const float* fcw     = (const float*)d_in[5];
  const float* fcb     = (const float*)d_in[6];
  int8_t* img = (int8_t*)d_ws;   // 288 KB weight image
  float* out = (float*)d_out;

  prep_weights<<<288, 64, 0, stream>>>(Wih, Whh, img);
  gru_main<<<64, 512, SMEM_SZ, stream>>>(hiddens, bih, bhh, fcw, fcb, img, out);
}

// Round 3
// 775.575 us; speedup vs baseline: 1.4172x; 1.0780x over previous
//
#include <hip/hip_runtime.h>
#include <stdint.h>

typedef int   v4i __attribute__((ext_vector_type(4)));
typedef float v4f __attribute__((ext_vector_type(4)));

// LDS map (bank-conflict-free act layout):
//   two act slots of 12288 B each, slot s base = s*SLOT_SZ
//   hi act byte (l, k, b): s*SLOT_SZ + l*2048 + (k>>4)*256 + b*16 + (k&15)
//   lo act byte: +LO_OFF
//   B-frag read for (l, kh): base + l*2048 + kh*1024 + lane*16  -> linear in lane
//   BIAS_OFF: fp32 PRE-SCALED bias [l][type R,Z,NX,NH][h]  (6144 B)
//   FC_OFF:   fc i8 A-frags, 2 blocks of 1KB
#define SLOT_SZ  12288
#define LO_OFF   6144
#define BIAS_OFF (2*SLOT_SZ)            // 24576
#define FC_OFF   (BIAS_OFF + 6144)      // 30720
#define SMEM_SZ  (FC_OFF + 2048)        // 32768

#define QW   1436.84056f      // 127/s, s = 1/sqrt(128)
#define C1f  4.38394754e-5f   // s*8/127^2  (hi-accum scale)
#define C2f  3.45193507e-7f   // C1/127     (lo-accum scale)
#define L2E  1.44269504f
// folded gate-combine constants: sigmoid gates carry -log2e, tanh gates 2*log2e
#define CR1  (-(L2E)*C1f)
#define CR2  (-(L2E)*C2f)
#define CX1  (2.0f*L2E*C1f)
#define CX2  (2.0f*L2E*C2f)

#define MFMA(A,B,C) __builtin_amdgcn_mfma_i32_16x16x64_i8(A, B, C, 0, 0, 0)

// i8 weight image (unchanged): blk = l*12 + o*2 + kh; o: 0 Rx,1 Rh,2 Zx,3 Zh,4 Nx,5 Nh.
// lane(g=lane&15, q=lane>>4) holds W[row g][k = kh*64 + q*16 + j], j=0..15.
__global__ void prep_weights(const float* __restrict__ Wih,
                             const float* __restrict__ Whh,
                             int8_t* __restrict__ img) {
  int bid = blockIdx.x, lane = threadIdx.x;          // 288 blocks x 64
  int w = bid / 36, blk = bid % 36;
  int l = blk / 12, rem = blk % 12, o = rem >> 1, kh = rem & 1;
  const float* M = (o & 1) ? Whh : Wih;
  int row = (o >> 1) * 128 + w * 16 + (lane & 15);
  int k0 = kh * 64 + (lane >> 4) * 16;
  const float* src = M + l * 49152 + row * 128 + k0;
  int words[4];
  #pragma unroll
  for (int j4 = 0; j4 < 4; ++j4) {
    unsigned wd = 0;
    #pragma unroll
    for (int j = 0; j < 4; ++j) {
      int q = (int)rintf(src[j4 * 4 + j] * QW);
      wd |= ((unsigned)(q & 255)) << (8 * j);
    }
    words[j4] = (int)wd;
  }
  *(v4i*)(img + (((long)bid) * 64 + lane) * 16) = *(const v4i*)words;
}

#define DECL_ACC v4i aRh={0,0,0,0},aRl={0,0,0,0},aZh={0,0,0,0},aZl={0,0,0,0}, \
                     aXh={0,0,0,0},aXl={0,0,0,0},aHh={0,0,0,0},aHl={0,0,0,0}

#define HMFMA(L,H0,LL0,H1,LL1) do { \
  aRh = MFMA(wr[(L)*12+2],  H0,  aRh);  aRl = MFMA(wr[(L)*12+2],  LL0, aRl); \
  aZh = MFMA(wr[(L)*12+6],  H0,  aZh);  aZl = MFMA(wr[(L)*12+6],  LL0, aZl); \
  aHh = MFMA(wr[(L)*12+10], H0,  aHh);  aHl = MFMA(wr[(L)*12+10], LL0, aHl); \
  aRh = MFMA(wr[(L)*12+3],  H1,  aRh);  aRl = MFMA(wr[(L)*12+3],  LL1, aRl); \
  aZh = MFMA(wr[(L)*12+7],  H1,  aZh);  aZl = MFMA(wr[(L)*12+7],  LL1, aZl); \
  aHh = MFMA(wr[(L)*12+11], H1,  aHh);  aHl = MFMA(wr[(L)*12+11], LL1, aHl); \
} while(0)

#define XMFMA(L,H0,LL0,H1,LL1) do { \
  aRh = MFMA(wr[(L)*12+0],  H0,  aRh);  aRl = MFMA(wr[(L)*12+0],  LL0, aRl); \
  aZh = MFMA(wr[(L)*12+4],  H0,  aZh);  aZl = MFMA(wr[(L)*12+4],  LL0, aZl); \
  aXh = MFMA(wr[(L)*12+8],  H0,  aXh);  aXl = MFMA(wr[(L)*12+8],  LL0, aXl); \
  aRh = MFMA(wr[(L)*12+1],  H1,  aRh);  aRl = MFMA(wr[(L)*12+1],  LL1, aRl); \
  aZh = MFMA(wr[(L)*12+5],  H1,  aZh);  aZl = MFMA(wr[(L)*12+5],  LL1, aZl); \
  aXh = MFMA(wr[(L)*12+9],  H1,  aXh);  aXl = MFMA(wr[(L)*12+9],  LL1, aXl); \
} while(0)

#define EW_WRITE(L, SN, BR, BZ, BX, BH) do { \
  unsigned hiw = 0, low = 0; \
  _Pragma("unroll") \
  for (int r = 0; r < 4; ++r) { \
    float gR = fmaf(CR1, (float)aRh[r], fmaf(CR2, (float)aRl[r], (BR)[r])); \
    float gZ = fmaf(CR1, (float)aZh[r], fmaf(CR2, (float)aZl[r], (BZ)[r])); \
    float gX = fmaf(CX1, (float)aXh[r], fmaf(CX2, (float)aXl[r], (BX)[r])); \
    float gH = fmaf(CX1, (float)aHh[r], fmaf(CX2, (float)aHl[r], (BH)[r])); \
    float rg = __builtin_amdgcn_rcpf(1.f + __builtin_amdgcn_exp2f(gR)); \
    float zg = __builtin_amdgcn_rcpf(1.f + __builtin_amdgcn_exp2f(gZ)); \
    float u  = __builtin_amdgcn_rcpf(1.f + __builtin_amdgcn_exp2f(fmaf(rg, gH, gX))); \
    float ng = fmaf(-2.f, u, 1.f); \
    float hn = fmaf(zg, hst[L][r] - ng, ng); \
    hst[L][r] = hn; \
    float f = hn * 15.875f, fhi = rintf(f); \
    hiw |= ((unsigned)(((int)fhi) & 255)) << (8 * r); \
    low |= ((unsigned)(((int)rintf((f - fhi) * 127.f)) & 255)) << (8 * r); \
  } \
  *(unsigned*)(ewb + (SN) + (L)*2048)          = hiw; \
  *(unsigned*)(ewb + (SN) + (L)*2048 + LO_OFF) = low; \
} while(0)

__global__ __launch_bounds__(512, 1)
void gru_main(const float* __restrict__ hiddens, const float* __restrict__ bih,
              const float* __restrict__ bhh, const float* __restrict__ fcw,
              const float* __restrict__ fcb, const int8_t* __restrict__ img,
              float* __restrict__ out) {
  extern __shared__ char smem[];
  const int tid = threadIdx.x, wg = blockIdx.x;
  const int lane = tid & 63, w = tid >> 6, col = lane & 15, q = lane >> 4;

  // ---- ALL 36 weight frags in registers ----
  v4i wr[36];
  #pragma unroll
  for (int i = 0; i < 36; ++i)
    wr[i] = *(const v4i*)(img + (((long)(w * 36 + i)) * 64 + lane) * 16);

  // ---- fc i8 A-frags in LDS ----
  if (tid < 128) {
    int kh = tid >> 6, ln = tid & 63, c2 = ln & 15, q2 = ln >> 4;
    int words[4] = {0, 0, 0, 0};
    if (c2 < 2) {
      const float* src = fcw + c2 * 128 + kh * 64 + q2 * 16;
      #pragma unroll
      for (int j4 = 0; j4 < 4; ++j4) {
        unsigned wd = 0;
        #pragma unroll
        for (int j = 0; j < 4; ++j) {
          int qv = (int)rintf(src[j4 * 4 + j] * QW);
          wd |= ((unsigned)(qv & 255)) << (8 * j);
        }
        words[j4] = (int)wd;
      }
    }
    *(v4i*)(smem + FC_OFF + kh * 1024 + ln * 16) = *(const v4i*)words;
  }
  // ---- bias table in LDS, PRE-SCALED for exp2-form gates ----
  for (int i = tid; i < 1536; i += 512) {
    int l = i >> 9, type = (i >> 7) & 3, h = i & 127;
    float bv;
    if      (type == 0) bv = -L2E * (bih[l * 384 + h]       + bhh[l * 384 + h]);
    else if (type == 1) bv = -L2E * (bih[l * 384 + 128 + h] + bhh[l * 384 + 128 + h]);
    else if (type == 2) bv = 2.0f * L2E * bih[l * 384 + 256 + h];
    else                bv = 2.0f * L2E * bhh[l * 384 + 256 + h];
    *(float*)(smem + BIAS_OFF + i * 4) = bv;
  }
  // ---- act slot0 init (hi/lo), chunked layout ----
  for (int i = tid; i < 6144; i += 512) {
    int l = i >> 11, b = (i >> 7) & 15, h = i & 127;
    float v = hiddens[((long)(wg * 16 + b)) * 384 + l * 128 + h];
    float f = v * 15.875f, fhi = rintf(f);
    int addr = l * 2048 + (h >> 4) * 256 + b * 16 + (h & 15);
    *(int8_t*)(smem + addr)          = (int8_t)(int)fhi;
    *(int8_t*)(smem + addr + LO_OFF) = (int8_t)(int)rintf((f - fhi) * 127.f);
  }
  // ---- h-state in regs: hst[l][r] = h[l][w*16+q*4+r][batch=col] ----
  v4f hst[3];
  #pragma unroll
  for (int l = 0; l < 3; ++l)
    #pragma unroll
    for (int r = 0; r < 4; ++r)
      hst[l][r] = hiddens[((long)(wg * 16 + col)) * 384 + l * 128 + w * 16 + q * 4 + r];

  const float fcb0 = fcb[0], fcb1 = fcb[1];
  __syncthreads();

  const char* fragb = smem + lane * 16;                 // linear frag base
  char* ewb = smem + w * 256 + col * 16 + q * 4;        // EW b32 write base (2-way, free)
  const char* biasb = smem + BIAS_OFF + (w * 16 + q * 4) * 4;

  // time-shared h prefetch block: serves l0 (loaded in prev l2) and l1 (reloaded mid-l0)
  v4i hh0 = *(const v4i*)(fragb + 0);
  v4i hl0 = *(const v4i*)(fragb + 0 + LO_OFF);
  v4i hh1 = *(const v4i*)(fragb + 1024);
  v4i hl1 = *(const v4i*)(fragb + 1024 + LO_OFF);
  v4i c2h0, c2l0, c2h1, c2l1;   // l0 x-frags cached for l2 h-side (same bytes)

  #pragma unroll 1
  for (int t = 0; t < 256; ++t) {
    const int so = (t & 1) * SLOT_SZ;
    const int sn = SLOT_SZ - so;

    // ================= layer 0 =================
    {
      DECL_ACC;
      // x-frags = prev-step layer-2 acts (read slot); double as l2 h cache
      c2h0 = *(const v4i*)(fragb + so + 2 * 2048);
      c2l0 = *(const v4i*)(fragb + so + 2 * 2048 + LO_OFF);
      c2h1 = *(const v4i*)(fragb + so + 2 * 2048 + 1024);
      c2l1 = *(const v4i*)(fragb + so + 2 * 2048 + 1024 + LO_OFF);
      v4f bRv = *(const v4f*)(biasb + 0 * 512);
      v4f bZv = *(const v4f*)(biasb + 1 * 512);
      v4f bXv = *(const v4f*)(biasb + 2 * 512);
      v4f bHv = *(const v4f*)(biasb + 3 * 512);
      HMFMA(0, hh0, hl0, hh1, hl1);          // h operands already in regs
      if (t > 0) XMFMA(0, c2h0, c2l0, c2h1, c2l1);
      // reload hpre <- l1 h-frags (stable since last step) for the l1 phase
      hh0 = *(const v4i*)(fragb + so + 2048);
      hl0 = *(const v4i*)(fragb + so + 2048 + LO_OFF);
      hh1 = *(const v4i*)(fragb + so + 2048 + 1024);
      hl1 = *(const v4i*)(fragb + so + 2048 + 1024 + LO_OFF);
      EW_WRITE(0, sn, bRv, bZv, bXv, bHv);
      __syncthreads();
    }
    // ================= layer 1 =================
    {
      DECL_ACC;
      v4i xh0 = *(const v4i*)(fragb + sn + 0);           // fresh layer-0 acts
      v4i xl0 = *(const v4i*)(fragb + sn + 0 + LO_OFF);
      v4i xh1 = *(const v4i*)(fragb + sn + 1024);
      v4i xl1 = *(const v4i*)(fragb + sn + 1024 + LO_OFF);
      v4f bRv = *(const v4f*)(biasb + 4 * 512);
      v4f bZv = *(const v4f*)(biasb + 5 * 512);
      v4f bXv = *(const v4f*)(biasb + 6 * 512);
      v4f bHv = *(const v4f*)(biasb + 7 * 512);
      HMFMA(1, hh0, hl0, hh1, hl1);          // register-ready at phase start
      XMFMA(1, xh0, xl0, xh1, xl1);
      EW_WRITE(1, sn, bRv, bZv, bXv, bHv);
      __syncthreads();
    }
    // ================= layer 2 =================
    {
      DECL_ACC;
      v4i xh0 = *(const v4i*)(fragb + sn + 2048);        // fresh layer-1 acts
      v4i xl0 = *(const v4i*)(fragb + sn + 2048 + LO_OFF);
      v4i xh1 = *(const v4i*)(fragb + sn + 2048 + 1024);
      v4i xl1 = *(const v4i*)(fragb + sn + 2048 + 1024 + LO_OFF);
      v4f bRv = *(const v4f*)(biasb + 8 * 512);
      v4f bZv = *(const v4f*)(biasb + 9 * 512);
      v4f bXv = *(const v4f*)(biasb + 10 * 512);
      v4f bHv = *(const v4f*)(biasb + 11 * 512);
      HMFMA(2, c2h0, c2l0, c2h1, c2l1);      // cached from l0, register-ready
      XMFMA(2, xh0, xl0, xh1, xl1);
      // prefetch next-step l0 h-frags (layer-0 acts written this step, barrier'd)
      hh0 = *(const v4i*)(fragb + sn + 0);
      hl0 = *(const v4i*)(fragb + sn + 0 + LO_OFF);
      hh1 = *(const v4i*)(fragb + sn + 1024);
      hl1 = *(const v4i*)(fragb + sn + 1024 + LO_OFF);
      EW_WRITE(2, sn, bRv, bZv, bXv, bHv);
      __syncthreads();
    }
    // ---- FC epilogue (wave 0): reads layer-2 acts just written (write slot) ----
    if (w == 0) {
      v4i dh = {0,0,0,0}, dl = {0,0,0,0};
      #pragma unroll
      for (int kh = 0; kh < 2; ++kh) {
        v4i xh = *(const v4i*)(fragb + sn + 2 * 2048 + kh * 1024);
        v4i xl = *(const v4i*)(fragb + sn + 2 * 2048 + kh * 1024 + LO_OFF);
        v4i fw = *(const v4i*)(smem + FC_OFF + kh * 1024 + lane * 16);
        dh = MFMA(fw, xh, dh);
        dl = MFMA(fw, xl, dl);
      }
      if (q == 0) {
        float2 o2;
        o2.x = fcb0 + C1f * (float)dh[0] + C2f * (float)dl[0];
        o2.y = fcb1 + C1f * (float)dh[1] + C2f * (float)dl[1];
        *(float2*)(out + (((long)(wg * 16 + col)) * 256 + t) * 2) = o2;
      }
    }
  }
}

extern "C" void kernel_launch(void* const* d_in, const int* in_sizes, int n_in,
                              void* d_out, int out_size, void* d_ws, size_t ws_size,
                              hipStream_t stream) {
  (void)in_sizes; (void)n_in; (void)out_size; (void)ws_size;
  const float* hiddens = (const float*)d_in[0];
  const float* Wih     = (const float*)d_in[1];
  const float* Whh     = (const float*)d_in[2];
  const float* bih     = (const float*)d_in[3];
  const float* bhh     = (const float*)d_in[4];
  const float* fcw     = (const float*)d_in[5];
  const float* fcb     = (const float*)d_in[6];
  int8_t* img = (int8_t*)d_ws;   // 288 KB weight image
  float* out = (float*)d_out;

  prep_weights<<<288, 64, 0, stream>>>(Wih, Whh, img);
  gru_main<<<64, 512, SMEM_SZ, stream>>>(hiddens, bih, bhh, fcw, fcb, img, out);
}

// Round 4
// 756.730 us; speedup vs baseline: 1.4525x; 1.0249x over previous
//
#include <hip/hip_runtime.h>
#include <stdint.h>

typedef int   v4i __attribute__((ext_vector_type(4)));
typedef float v4f __attribute__((ext_vector_type(4)));

// LDS map (bank-conflict-free act layout):
//   two act slots of 12288 B each, slot s base = s*SLOT_SZ
//   hi act byte (l, k, b): s*SLOT_SZ + l*2048 + (k>>4)*256 + b*16 + (k&15)
//   lo act byte: +LO_OFF
//   B-frag read for (l, kh): base + l*2048 + kh*1024 + lane*16  -> linear in lane
//   BIAS_OFF: fp32 PRE-SCALED bias [l][type R,Z,NX,NH][h]  (6144 B)
//   FC_OFF:   fc i8 A-frags, 2 blocks of 1KB
#define SLOT_SZ  12288
#define LO_OFF   6144
#define BIAS_OFF (2*SLOT_SZ)            // 24576
#define FC_OFF   (BIAS_OFF + 6144)      // 30720
#define SMEM_SZ  (FC_OFF + 2048)        // 32768

#define QW   1436.84056f      // 127/s, s = 1/sqrt(128)
#define C1f  4.38394754e-5f   // s*8/127^2  (hi-accum scale)
#define C2f  3.45193507e-7f   // C1/127     (lo-accum scale)
#define L2E  1.44269504f
// folded gate-combine constants: sigmoid gates carry -log2e, tanh gates 2*log2e
#define CR1  (-(L2E)*C1f)
#define CR2  (-(L2E)*C2f)
#define CX1  (2.0f*L2E*C1f)
#define CX2  (2.0f*L2E*C2f)

#define MFMA(A,B,C) __builtin_amdgcn_mfma_i32_16x16x64_i8(A, B, C, 0, 0, 0)

// i8 weight image (unchanged): blk = l*12 + o*2 + kh; o: 0 Rx,1 Rh,2 Zx,3 Zh,4 Nx,5 Nh.
// lane(g=lane&15, q=lane>>4) holds W[row g][k = kh*64 + q*16 + j], j=0..15.
__global__ void prep_weights(const float* __restrict__ Wih,
                             const float* __restrict__ Whh,
                             int8_t* __restrict__ img) {
  int bid = blockIdx.x, lane = threadIdx.x;          // 288 blocks x 64
  int w = bid / 36, blk = bid % 36;
  int l = blk / 12, rem = blk % 12, o = rem >> 1, kh = rem & 1;
  const float* M = (o & 1) ? Whh : Wih;
  int row = (o >> 1) * 128 + w * 16 + (lane & 15);
  int k0 = kh * 64 + (lane >> 4) * 16;
  const float* src = M + l * 49152 + row * 128 + k0;
  int words[4];
  #pragma unroll
  for (int j4 = 0; j4 < 4; ++j4) {
    unsigned wd = 0;
    #pragma unroll
    for (int j = 0; j < 4; ++j) {
      int q = (int)rintf(src[j4 * 4 + j] * QW);
      wd |= ((unsigned)(q & 255)) << (8 * j);
    }
    words[j4] = (int)wd;
  }
  *(v4i*)(img + (((long)bid) * 64 + lane) * 16) = *(const v4i*)words;
}

#define DECL_ACC v4i aRh={0,0,0,0},aRl={0,0,0,0},aZh={0,0,0,0},aZl={0,0,0,0}, \
                     aXh={0,0,0,0},aXl={0,0,0,0},aHh={0,0,0,0},aHl={0,0,0,0}

#define HMFMA(L,H0,LL0,H1,LL1) do { \
  aRh = MFMA(wr[(L)*12+2],  H0,  aRh);  aRl = MFMA(wr[(L)*12+2],  LL0, aRl); \
  aZh = MFMA(wr[(L)*12+6],  H0,  aZh);  aZl = MFMA(wr[(L)*12+6],  LL0, aZl); \
  aHh = MFMA(wr[(L)*12+10], H0,  aHh);  aHl = MFMA(wr[(L)*12+10], LL0, aHl); \
  aRh = MFMA(wr[(L)*12+3],  H1,  aRh);  aRl = MFMA(wr[(L)*12+3],  LL1, aRl); \
  aZh = MFMA(wr[(L)*12+7],  H1,  aZh);  aZl = MFMA(wr[(L)*12+7],  LL1, aZl); \
  aHh = MFMA(wr[(L)*12+11], H1,  aHh);  aHl = MFMA(wr[(L)*12+11], LL1, aHl); \
} while(0)

#define XMFMA(L,H0,LL0,H1,LL1) do { \
  aRh = MFMA(wr[(L)*12+0],  H0,  aRh);  aRl = MFMA(wr[(L)*12+0],  LL0, aRl); \
  aZh = MFMA(wr[(L)*12+4],  H0,  aZh);  aZl = MFMA(wr[(L)*12+4],  LL0, aZl); \
  aXh = MFMA(wr[(L)*12+8],  H0,  aXh);  aXl = MFMA(wr[(L)*12+8],  LL0, aXl); \
  aRh = MFMA(wr[(L)*12+1],  H1,  aRh);  aRl = MFMA(wr[(L)*12+1],  LL1, aRl); \
  aZh = MFMA(wr[(L)*12+5],  H1,  aZh);  aZl = MFMA(wr[(L)*12+5],  LL1, aZl); \
  aXh = MFMA(wr[(L)*12+9],  H1,  aXh);  aXl = MFMA(wr[(L)*12+9],  LL1, aXl); \
} while(0)

// EW with v_perm byte packing (bit-identical values, ~16 fewer VALU ops)
#define EW_WRITE(L, SN, BR, BZ, BX, BH) do { \
  int hi_i[4], lo_i[4]; \
  _Pragma("unroll") \
  for (int r = 0; r < 4; ++r) { \
    float gR = fmaf(CR1, (float)aRh[r], fmaf(CR2, (float)aRl[r], (BR)[r])); \
    float gZ = fmaf(CR1, (float)aZh[r], fmaf(CR2, (float)aZl[r], (BZ)[r])); \
    float gX = fmaf(CX1, (float)aXh[r], fmaf(CX2, (float)aXl[r], (BX)[r])); \
    float gH = fmaf(CX1, (float)aHh[r], fmaf(CX2, (float)aHl[r], (BH)[r])); \
    float rg = __builtin_amdgcn_rcpf(1.f + __builtin_amdgcn_exp2f(gR)); \
    float zg = __builtin_amdgcn_rcpf(1.f + __builtin_amdgcn_exp2f(gZ)); \
    float u  = __builtin_amdgcn_rcpf(1.f + __builtin_amdgcn_exp2f(fmaf(rg, gH, gX))); \
    float ng = fmaf(-2.f, u, 1.f); \
    float hn = fmaf(zg, hst[L][r] - ng, ng); \
    hst[L][r] = hn; \
    float f = hn * 15.875f, fhi = rintf(f); \
    hi_i[r] = (int)fhi; \
    lo_i[r] = (int)rintf((f - fhi) * 127.f); \
  } \
  unsigned ph01 = __builtin_amdgcn_perm((unsigned)hi_i[1], (unsigned)hi_i[0], 0x00000400u); \
  unsigned ph23 = __builtin_amdgcn_perm((unsigned)hi_i[3], (unsigned)hi_i[2], 0x04000000u); \
  unsigned hiw  = __builtin_amdgcn_perm(ph23, ph01, 0x07060100u); \
  unsigned pl01 = __builtin_amdgcn_perm((unsigned)lo_i[1], (unsigned)lo_i[0], 0x00000400u); \
  unsigned pl23 = __builtin_amdgcn_perm((unsigned)lo_i[3], (unsigned)lo_i[2], 0x04000000u); \
  unsigned low  = __builtin_amdgcn_perm(pl23, pl01, 0x07060100u); \
  *(unsigned*)(ewb + (SN) + (L)*2048)          = hiw; \
  *(unsigned*)(ewb + (SN) + (L)*2048 + LO_OFF) = low; \
} while(0)

__global__ __launch_bounds__(512, 1)
void gru_main(const float* __restrict__ hiddens, const float* __restrict__ bih,
              const float* __restrict__ bhh, const float* __restrict__ fcw,
              const float* __restrict__ fcb, const int8_t* __restrict__ img,
              float* __restrict__ out) {
  extern __shared__ char smem[];
  const int tid = threadIdx.x, wg = blockIdx.x;
  const int lane = tid & 63, w = tid >> 6, col = lane & 15, q = lane >> 4;

  // ---- ALL 36 weight frags in registers ----
  v4i wr[36];
  #pragma unroll
  for (int i = 0; i < 36; ++i)
    wr[i] = *(const v4i*)(img + (((long)(w * 36 + i)) * 64 + lane) * 16);

  // ---- fc i8 A-frags in LDS ----
  if (tid < 128) {
    int kh = tid >> 6, ln = tid & 63, c2 = ln & 15, q2 = ln >> 4;
    int words[4] = {0, 0, 0, 0};
    if (c2 < 2) {
      const float* src = fcw + c2 * 128 + kh * 64 + q2 * 16;
      #pragma unroll
      for (int j4 = 0; j4 < 4; ++j4) {
        unsigned wd = 0;
        #pragma unroll
        for (int j = 0; j < 4; ++j) {
          int qv = (int)rintf(src[j4 * 4 + j] * QW);
          wd |= ((unsigned)(qv & 255)) << (8 * j);
        }
        words[j4] = (int)wd;
      }
    }
    *(v4i*)(smem + FC_OFF + kh * 1024 + ln * 16) = *(const v4i*)words;
  }
  // ---- bias table in LDS, PRE-SCALED for exp2-form gates ----
  for (int i = tid; i < 1536; i += 512) {
    int l = i >> 9, type = (i >> 7) & 3, h = i & 127;
    float bv;
    if      (type == 0) bv = -L2E * (bih[l * 384 + h]       + bhh[l * 384 + h]);
    else if (type == 1) bv = -L2E * (bih[l * 384 + 128 + h] + bhh[l * 384 + 128 + h]);
    else if (type == 2) bv = 2.0f * L2E * bih[l * 384 + 256 + h];
    else                bv = 2.0f * L2E * bhh[l * 384 + 256 + h];
    *(float*)(smem + BIAS_OFF + i * 4) = bv;
  }
  // ---- act slot0 init (hi/lo), chunked layout ----
  for (int i = tid; i < 6144; i += 512) {
    int l = i >> 11, b = (i >> 7) & 15, h = i & 127;
    float v = hiddens[((long)(wg * 16 + b)) * 384 + l * 128 + h];
    float f = v * 15.875f, fhi = rintf(f);
    int addr = l * 2048 + (h >> 4) * 256 + b * 16 + (h & 15);
    *(int8_t*)(smem + addr)          = (int8_t)(int)fhi;
    *(int8_t*)(smem + addr + LO_OFF) = (int8_t)(int)rintf((f - fhi) * 127.f);
  }
  // ---- h-state in regs: hst[l][r] = h[l][w*16+q*4+r][batch=col] ----
  v4f hst[3];
  #pragma unroll
  for (int l = 0; l < 3; ++l)
    #pragma unroll
    for (int r = 0; r < 4; ++r)
      hst[l][r] = hiddens[((long)(wg * 16 + col)) * 384 + l * 128 + w * 16 + q * 4 + r];

  const float fcb0 = fcb[0], fcb1 = fcb[1];
  __syncthreads();

  const char* fragb = smem + lane * 16;                 // linear frag base
  char* ewb = smem + w * 256 + col * 16 + q * 4;        // EW b32 write base (2-way, free)
  const char* biasb = smem + BIAS_OFF + (w * 16 + q * 4) * 4;

  // Persistent act-frag registers (read-once dedup):
  //   A = l0 acts @t-1 (h-side of l0; refilled by l1's x-read)
  //   B = l1 acts @t-1 (h-side of l1; refilled by l2's x-read)
  //   C = l2 acts @t-1 (x-side of l0 AND h-side of l2 AND FC@t-1; read in l0)
  v4i Ah0 = *(const v4i*)(fragb + 0);
  v4i Al0 = *(const v4i*)(fragb + 0 + LO_OFF);
  v4i Ah1 = *(const v4i*)(fragb + 1024);
  v4i Al1 = *(const v4i*)(fragb + 1024 + LO_OFF);
  v4i Bh0 = *(const v4i*)(fragb + 2048);
  v4i Bl0 = *(const v4i*)(fragb + 2048 + LO_OFF);
  v4i Bh1 = *(const v4i*)(fragb + 2048 + 1024);
  v4i Bl1 = *(const v4i*)(fragb + 2048 + 1024 + LO_OFF);
  v4i Ch0, Cl0, Ch1, Cl1;

  #pragma unroll 1
  for (int t = 0; t < 256; ++t) {
    const int so = (t & 1) * SLOT_SZ;
    const int sn = SLOT_SZ - so;

    // ================= layer 0 (+ FC for step t-1) =================
    {
      DECL_ACC;
      // x-frags = prev-step layer-2 acts (read slot) -> C (also l2 h, FC input)
      Ch0 = *(const v4i*)(fragb + so + 2 * 2048);
      Cl0 = *(const v4i*)(fragb + so + 2 * 2048 + LO_OFF);
      Ch1 = *(const v4i*)(fragb + so + 2 * 2048 + 1024);
      Cl1 = *(const v4i*)(fragb + so + 2 * 2048 + 1024 + LO_OFF);
      v4f bRv = *(const v4f*)(biasb + 0 * 512);
      v4f bZv = *(const v4f*)(biasb + 1 * 512);
      v4f bXv = *(const v4f*)(biasb + 2 * 512);
      v4f bHv = *(const v4f*)(biasb + 3 * 512);
      HMFMA(0, Ah0, Al0, Ah1, Al1);          // h operands already in regs
      if (t > 0) {
        XMFMA(0, Ch0, Cl0, Ch1, Cl1);
        // ---- FC for step t-1 (wave 0): same C-frags, overlaps l0 MFMAs ----
        if (w == 0) {
          v4i dh = {0,0,0,0}, dl = {0,0,0,0};
          v4i fwA = *(const v4i*)(smem + FC_OFF + 0 * 1024 + lane * 16);
          v4i fwB = *(const v4i*)(smem + FC_OFF + 1 * 1024 + lane * 16);
          dh = MFMA(fwA, Ch0, dh);  dl = MFMA(fwA, Cl0, dl);
          dh = MFMA(fwB, Ch1, dh);  dl = MFMA(fwB, Cl1, dl);
          if (q == 0) {
            float2 o2;
            o2.x = fcb0 + C1f * (float)dh[0] + C2f * (float)dl[0];
            o2.y = fcb1 + C1f * (float)dh[1] + C2f * (float)dl[1];
            *(float2*)(out + (((long)(wg * 16 + col)) * 256 + (t - 1)) * 2) = o2;
          }
        }
      }
      EW_WRITE(0, sn, bRv, bZv, bXv, bHv);
      __syncthreads();
    }
    // ================= layer 1 =================
    {
      DECL_ACC;
      // fresh layer-0 acts -> A (x now, l0 h-side next step)
      Ah0 = *(const v4i*)(fragb + sn + 0);
      Al0 = *(const v4i*)(fragb + sn + 0 + LO_OFF);
      Ah1 = *(const v4i*)(fragb + sn + 1024);
      Al1 = *(const v4i*)(fragb + sn + 1024 + LO_OFF);
      v4f bRv = *(const v4f*)(biasb + 4 * 512);
      v4f bZv = *(const v4f*)(biasb + 5 * 512);
      v4f bXv = *(const v4f*)(biasb + 6 * 512);
      v4f bHv = *(const v4f*)(biasb + 7 * 512);
      HMFMA(1, Bh0, Bl0, Bh1, Bl1);          // register-ready at phase start
      XMFMA(1, Ah0, Al0, Ah1, Al1);
      EW_WRITE(1, sn, bRv, bZv, bXv, bHv);
      __syncthreads();
    }
    // ================= layer 2 =================
    {
      DECL_ACC;
      // fresh layer-1 acts -> B (x now, l1 h-side next step)
      Bh0 = *(const v4i*)(fragb + sn + 2048);
      Bl0 = *(const v4i*)(fragb + sn + 2048 + LO_OFF);
      Bh1 = *(const v4i*)(fragb + sn + 2048 + 1024);
      Bl1 = *(const v4i*)(fragb + sn + 2048 + 1024 + LO_OFF);
      v4f bRv = *(const v4f*)(biasb + 8 * 512);
      v4f bZv = *(const v4f*)(biasb + 9 * 512);
      v4f bXv = *(const v4f*)(biasb + 10 * 512);
      v4f bHv = *(const v4f*)(biasb + 11 * 512);
      HMFMA(2, Ch0, Cl0, Ch1, Cl1);          // C read in l0, register-ready
      XMFMA(2, Bh0, Bl0, Bh1, Bl1);
      EW_WRITE(2, sn, bRv, bZv, bXv, bHv);
      __syncthreads();
    }
  }
  // ---- FC for the final step t=255 (acts in slot 0, layer 2) ----
  if (w == 0) {
    v4i dh = {0,0,0,0}, dl = {0,0,0,0};
    v4i xh0 = *(const v4i*)(fragb + 2 * 2048);
    v4i xl0 = *(const v4i*)(fragb + 2 * 2048 + LO_OFF);
    v4i xh1 = *(const v4i*)(fragb + 2 * 2048 + 1024);
    v4i xl1 = *(const v4i*)(fragb + 2 * 2048 + 1024 + LO_OFF);
    v4i fwA = *(const v4i*)(smem + FC_OFF + 0 * 1024 + lane * 16);
    v4i fwB = *(const v4i*)(smem + FC_OFF + 1 * 1024 + lane * 16);
    dh = MFMA(fwA, xh0, dh);  dl = MFMA(fwA, xl0, dl);
    dh = MFMA(fwB, xh1, dh);  dl = MFMA(fwB, xl1, dl);
    if (q == 0) {
      float2 o2;
      o2.x = fcb0 + C1f * (float)dh[0] + C2f * (float)dl[0];
      o2.y = fcb1 + C1f * (float)dh[1] + C2f * (float)dl[1];
      *(float2*)(out + (((long)(wg * 16 + col)) * 256 + 255) * 2) = o2;
    }
  }
}

extern "C" void kernel_launch(void* const* d_in, const int* in_sizes, int n_in,
                              void* d_out, int out_size, void* d_ws, size_t ws_size,
                              hipStream_t stream) {
  (void)in_sizes; (void)n_in; (void)out_size; (void)ws_size;
  const float* hiddens = (const float*)d_in[0];
  const float* Wih     = (const float*)d_in[1];
  const float* Whh     = (const float*)d_in[2];
  const float* bih     = (const float*)d_in[3];
  const float* bhh     = (const float*)d_in[4];
  const float* fcw     = (const float*)d_in[5];
  const float* fcb     = (const float*)d_in[6];
  int8_t* img = (int8_t*)d_ws;   // 288 KB weight image
  float* out = (float*)d_out;

  prep_weights<<<288, 64, 0, stream>>>(Wih, Whh, img);
  gru_main<<<64, 512, SMEM_SZ, stream>>>(hiddens, bih, bhh, fcw, fcb, img, out);
}